// Round 23
// baseline (107.923 us; speedup 1.0000x reference)
//
#include <hip/hip_runtime.h>
#include <hip/hip_bf16.h>

// Problem: T=255, B=256, NIN=784, NOUT=40
// out layout: [spk_rec (255*256*40) | mem_rec (255*256*40)] fp32
#define T_STEPS 255
#define BATCH 256
#define NIN 784
#define NOUT 40
#define MROWS (T_STEPS * BATCH)          // 65280
#define TBN (T_STEPS * BATCH * NOUT)     // 2611200
#define BN_CH (BATCH * NOUT)             // 10240

#define BM 64         // rows per block -> grid 1020 -> 3 blocks/CU resident
#define NCH 25        // K padded to 800 = 25 chunks of 32
#define WB_CHUNK 4608 // bf16 per chunk: 3 splits x 3 ntiles x 64 lanes x 8
#define EPS_NEAR 2e-4f
#define SCH 30        // scan chunk length (measured-best cfg)

typedef short bf16x8 __attribute__((ext_vector_type(8)));
typedef float f32x4 __attribute__((ext_vector_type(4)));

__device__ __forceinline__ unsigned short f2bf(float f) {  // RNE
  unsigned u = __float_as_uint(f);
  u += 0x7fffu + ((u >> 16) & 1u);
  return (unsigned short)(u >> 16);
}
__device__ __forceinline__ float bf2f(unsigned short h) {
  return __uint_as_float(((unsigned)h) << 16);
}

// Pre-split W into fragment-major bf16 (3 exact-residual levels). 230 KB.
__global__ __launch_bounds__(256) void wsplit_kernel(
    const float* __restrict__ W, unsigned short* __restrict__ Wbg,
    int* __restrict__ count) {
  int i = blockIdx.x * 256 + threadIdx.x;
  if (i == 0) *count = 0;
  if (i >= NCH * WB_CHUNK) return;
  int e = i & 7, l = (i >> 3) & 63, t = (i >> 9) % 3, s = (i / 1536) % 3,
      c = i / 4608;
  int k = c * 32 + (l >> 4) * 8 + e;
  int n = t * 16 + (l & 15);
  float v = (n < NOUT && k < NIN) ? W[n * NIN + k] : 0.f;
  unsigned short h1 = f2bf(v);
  float r1 = v - bf2f(h1);
  unsigned short h2 = f2bf(r1);
  float r2 = r1 - bf2f(h2);
  unsigned short h3 = f2bf(r2);
  Wbg[i] = (s == 0) ? h1 : (s == 1) ? h2 : h3;
}

// Split-precision bf16 MFMA GEMM — per-element math identical to the
// validated 107us kernel. Occupancy experiment (isolating R18's confound):
// BM=64 -> grid 1020 -> 3 blocks/CU (12 waves/CU vs 8), B kept
// DOUBLE-BUFFERED in registers (no per-chunk B stall), X LDS dbuf,
// lgkmcnt-only barriers (R22, neutral-validated).
__global__ __launch_bounds__(256, 3) void lif_gemm_mfma(
    const float* __restrict__ X, const unsigned short* __restrict__ Wbg,
    float* __restrict__ cur) {
  alignas(16) __shared__ float xs0[2048];  // 512 slots x 16B (8 KB)
  alignas(16) __shared__ float xs1[2048];
  const int tid = threadIdx.x;
  const int m0 = blockIdx.x * BM;
  const int w = tid >> 6, l = tid & 63;
  const int lr = l & 15, lg = l >> 4;

  f32x4 acc[3];
#pragma unroll
  for (int t = 0; t < 3; ++t) acc[t] = (f32x4){0.f, 0.f, 0.f, 0.f};

  float4 gxA[2], gxB[2];
  bf16x8 BA[9], BB[9];

// LDS-ordered barrier without the vmcnt(0) drain (R22-validated).
#define BAR()                                                             \
  do {                                                                    \
    asm volatile("s_waitcnt lgkmcnt(0)" ::: "memory");                    \
    __builtin_amdgcn_s_barrier();                                         \
  } while (0)

#define LOADX(C, DST)                                                     \
  do {                                                                    \
    const int k0_ = (C) * 32;                                             \
    _Pragma("unroll")                                                     \
    for (int i = 0; i < 2; ++i) {                                         \
      int S = tid + i * 256;                                              \
      int row = S >> 3;                                                   \
      int c4 = (S & 7) ^ (row & 7);                                       \
      int k = k0_ + c4 * 4;                                               \
      float4 v = make_float4(0.f, 0.f, 0.f, 0.f);                         \
      if (k < NIN)                                                        \
        v = *reinterpret_cast<const float4*>(X + (size_t)(m0 + row) * NIN + k); \
      DST[i] = v;                                                         \
    }                                                                     \
  } while (0)

#define LOADB(C, DST)                                                     \
  do {                                                                    \
    const unsigned short* base_ = Wbg + (size_t)(C) * WB_CHUNK;           \
    _Pragma("unroll")                                                     \
    for (int q = 0; q < 9; ++q)                                           \
      DST[q] = *reinterpret_cast<const bf16x8*>(base_ + (q * 64 + l) * 8); \
  } while (0)

#define WRITEX(BUF, SRC)                                                  \
  do {                                                                    \
    _Pragma("unroll")                                                     \
    for (int i = 0; i < 2; ++i) {                                         \
      int S = tid + i * 256;                                              \
      *reinterpret_cast<float4*>(&(BUF)[S * 4]) = SRC[i];                 \
    }                                                                     \
  } while (0)

#define COMPUTE(BUF, BSET)                                                \
  do {                                                                    \
    int row = w * 16 + lr;                                                \
    int sA = row * 8 + ((lg * 2) ^ (row & 7));                            \
    int sB = row * 8 + ((lg * 2 + 1) ^ (row & 7));                        \
    float4 fa = *reinterpret_cast<float4*>(&(BUF)[sA * 4]);               \
    float4 fb = *reinterpret_cast<float4*>(&(BUF)[sB * 4]);               \
    float f[8] = {fa.x, fa.y, fa.z, fa.w, fb.x, fb.y, fb.z, fb.w};        \
    union U { unsigned d[4]; bf16x8 v; } A1, A2, A3;                      \
    _Pragma("unroll")                                                     \
    for (int d = 0; d < 4; ++d) {                                         \
      float e0 = f[2 * d], e1 = f[2 * d + 1];                             \
      unsigned short h0 = f2bf(e0), h1 = f2bf(e1);                        \
      float r0 = e0 - bf2f(h0), r1 = e1 - bf2f(h1);                       \
      unsigned short g0 = f2bf(r0), g1 = f2bf(r1);                        \
      float s0 = r0 - bf2f(g0), s1 = r1 - bf2f(g1);                       \
      A1.d[d] = (unsigned)h0 | ((unsigned)h1 << 16);                      \
      A2.d[d] = (unsigned)g0 | ((unsigned)g1 << 16);                      \
      A3.d[d] = (unsigned)f2bf(s0) | ((unsigned)f2bf(s1) << 16);          \
    }                                                                     \
    _Pragma("unroll")                                                     \
    for (int t = 0; t < 3; ++t) {                                         \
      acc[t] = __builtin_amdgcn_mfma_f32_16x16x32_bf16(A3.v, BSET[0 * 3 + t], acc[t], 0, 0, 0); \
      acc[t] = __builtin_amdgcn_mfma_f32_16x16x32_bf16(A1.v, BSET[2 * 3 + t], acc[t], 0, 0, 0); \
      acc[t] = __builtin_amdgcn_mfma_f32_16x16x32_bf16(A2.v, BSET[1 * 3 + t], acc[t], 0, 0, 0); \
      acc[t] = __builtin_amdgcn_mfma_f32_16x16x32_bf16(A2.v, BSET[0 * 3 + t], acc[t], 0, 0, 0); \
      acc[t] = __builtin_amdgcn_mfma_f32_16x16x32_bf16(A1.v, BSET[1 * 3 + t], acc[t], 0, 0, 0); \
      acc[t] = __builtin_amdgcn_mfma_f32_16x16x32_bf16(A1.v, BSET[0 * 3 + t], acc[t], 0, 0, 0); \
    }                                                                     \
  } while (0)

  // prologue: chunk0 -> buf0, chunk1 -> regs
  LOADX(0, gxA);
  WRITEX(xs0, gxA);
  LOADX(1, gxB);
  LOADB(0, BA);
  LOADB(1, BB);
  BAR();

  // chunks 0..23 in pairs; chunk 24 in epilogue.
  for (int c = 0; c < 24; c += 2) {
    // even chunk c: buf xs0 / BA
    if (c + 2 < NCH) LOADX(c + 2, gxA);
    COMPUTE(xs0, BA);
    if (c + 2 < NCH) LOADB(c + 2, BA);
    WRITEX(xs1, gxB);          // stage chunk c+1 (issued during c-1)
    BAR();
    // odd chunk c+1: buf xs1 / BB
    if (c + 3 < NCH) LOADX(c + 3, gxB);
    COMPUTE(xs1, BB);
    if (c + 3 < NCH) LOADB(c + 3, BB);
    if (c + 2 < NCH) WRITEX(xs0, gxA);  // stage chunk c+2
    BAR();
  }
  COMPUTE(xs0, BA);  // chunk 24
#undef LOADX
#undef LOADB
#undef WRITEX
#undef COMPUTE
#undef BAR

  // D layout (m89-verified): col = lane&15, row = (lane>>4)*4 + reg
#pragma unroll
  for (int t = 0; t < 3; ++t)
#pragma unroll
    for (int r = 0; r < 4; ++r) {
      int col = t * 16 + lr;
      if (col < NOUT) {
        size_t grow = (size_t)m0 + w * 16 + lg * 4 + r;
        cur[grow * NOUT + col] = acc[t][r];
      }
    }
}

// Validated scan math + near-boundary chain flagging; 30-step chunks with
// next-chunk prefetch (measured-best config).
__global__ __launch_bounds__(64) void lif_scan_kernel(
    float* __restrict__ spk, float* __restrict__ curmem,
    int* __restrict__ count, int* __restrict__ wlist) {
  const int idx = blockIdx.x * 64 + threadIdx.x;
  float mem = 0.f;
  bool near = false;
  float c[SCH];
#pragma unroll
  for (int i = 0; i < SCH; ++i) c[i] = curmem[(size_t)i * BN_CH + idx];
  for (int ch = 0; ch < 9; ++ch) {
    const int t0 = ch * SCH;
    float nx[SCH];
    if (ch != 8) {
#pragma unroll
      for (int i = 0; i < SCH; ++i) {
        int t = t0 + SCH + i;
        nx[i] = (t < T_STEPS) ? curmem[(size_t)t * BN_CH + idx] : 0.f;
      }
    }
#pragma unroll
    for (int i = 0; i < SCH; ++i) {
      if (t0 + i < T_STEPS) {
        float reset = (mem > 1.0f) ? 1.0f : 0.0f;
        float decay = 0.95f * mem;
        asm volatile("" : "+v"(decay));  // forbid fma contraction
        float summ = decay + c[i];
        float mnew = summ * (1.0f - reset);
        near = near || (fabsf(mnew - 1.0f) < EPS_NEAR);
        curmem[(size_t)(t0 + i) * BN_CH + idx] = mnew;
        spk[(size_t)(t0 + i) * BN_CH + idx] = (mnew > 1.0f) ? 1.0f : 0.0f;
        mem = mnew;
      }
    }
    if (ch != 8) {
#pragma unroll
      for (int i = 0; i < SCH; ++i) c[i] = nx[i];
    }
  }
  if (near) {
    int p = atomicAdd(count, 1);
    wlist[p] = idx;
  }
}

// PARALLEL chain re-dot (validated path): one wave per (flagged chain,
// 8-t block), grid-strided; fp64 dot rounded to fp32 into curfix.
__global__ __launch_bounds__(256) void chaindot_kernel(
    const float* __restrict__ X, const float* __restrict__ W,
    const int* __restrict__ count, const int* __restrict__ wlist,
    float* __restrict__ curfix) {
  const int wv0 = blockIdx.x * 4 + (threadIdx.x >> 6);
  const int l = threadIdx.x & 63;
  const int njobs = *count * 32;
  for (int job = wv0; job < njobs; job += 10240) {
    const int f = job >> 5;
    const int tb = (job & 31) * 8;
    const int idx = wlist[f];
    const int b = idx / NOUT, n = idx % NOUT;
    double wreg[13];
#pragma unroll
    for (int j = 0; j < 12; ++j) wreg[j] = (double)W[n * NIN + l + j * 64];
    wreg[12] = (l < 16) ? (double)W[n * NIN + 768 + l] : 0.0;
#pragma unroll
    for (int u = 0; u < 8; ++u) {
      int t = tb + u;
      if (t >= T_STEPS) break;
      const float* xr = X + (size_t)(t * BATCH + b) * NIN;
      double s = 0.0;
#pragma unroll
      for (int j = 0; j < 12; ++j) s = fma((double)xr[l + j * 64], wreg[j], s);
      if (l < 16) s = fma((double)xr[768 + l], wreg[12], s);
#pragma unroll
      for (int off = 32; off; off >>= 1) s += __shfl_xor(s, off);
      if (l == 0) curfix[(size_t)f * T_STEPS + t] = (float)s;
    }
  }
}

// Serial scan replay for flagged chains from curfix (15-deep prefetch);
// overwrites spk/mem (validated path).
__global__ __launch_bounds__(64) void chainscan_kernel(
    float* __restrict__ spk, float* __restrict__ memout,
    const int* __restrict__ count, const int* __restrict__ wlist,
    const float* __restrict__ curfix) {
  const int f = blockIdx.x * 64 + threadIdx.x;
  if (f >= *count) return;
  const int idx = wlist[f];
  const float* cf = curfix + (size_t)f * T_STEPS;
  float mem = 0.f;
  float c[15];
#pragma unroll
  for (int i = 0; i < 15; ++i) c[i] = cf[i];
  for (int ch = 0; ch < 17; ++ch) {
    const int t0 = ch * 15;
    float nx[15];
    if (ch != 16) {
#pragma unroll
      for (int i = 0; i < 15; ++i) nx[i] = cf[t0 + 15 + i];
    }
#pragma unroll
    for (int i = 0; i < 15; ++i) {
      float reset = (mem > 1.0f) ? 1.0f : 0.0f;
      float decay = 0.95f * mem;
      asm volatile("" : "+v"(decay));
      float summ = decay + c[i];
      float mnew = summ * (1.0f - reset);
      spk[(size_t)(t0 + i) * BN_CH + idx] = (mnew > 1.0f) ? 1.0f : 0.0f;
      memout[(size_t)(t0 + i) * BN_CH + idx] = mnew;
      mem = mnew;
    }
    if (ch != 16) {
#pragma unroll
      for (int i = 0; i < 15; ++i) c[i] = nx[i];
    }
  }
}

extern "C" void kernel_launch(void* const* d_in, const int* in_sizes, int n_in,
                              void* d_out, int out_size, void* d_ws,
                              size_t ws_size, hipStream_t stream) {
  (void)in_sizes; (void)n_in; (void)out_size; (void)ws_size;
  const float* X = (const float*)d_in[0];
  const float* W = (const float*)d_in[1];
  float* out = (float*)d_out;
  float* spk = out;            // [255,256,40]
  float* memout = out + TBN;   // [255,256,40]: cur scratch then mem
  char* ws = (char*)d_ws;
  int* count = (int*)ws;
  int* wlist = (int*)(ws + 64);                        // 10240 ints
  unsigned short* Wbg = (unsigned short*)(ws + 41024); // 230400 B
  float* curfix = (float*)(ws + 271424);               // 10240x255 fp32

  wsplit_kernel<<<(NCH * WB_CHUNK + 255) / 256, 256, 0, stream>>>(W, Wbg,
                                                                  count);
  lif_gemm_mfma<<<MROWS / BM, 256, 0, stream>>>(X, Wbg, memout);
  lif_scan_kernel<<<BN_CH / 64, 64, 0, stream>>>(spk, memout, count, wlist);
  chaindot_kernel<<<2560, 256, 0, stream>>>(X, W, count, wlist, curfix);
  chainscan_kernel<<<BN_CH / 64, 64, 0, stream>>>(spk, memout, count, wlist,
                                                  curfix);
}

// Round 24
// 100.115 us; speedup vs baseline: 1.0780x; 1.0780x over previous
//
#include <hip/hip_runtime.h>
#include <hip/hip_bf16.h>

// Problem: T=255, B=256, NIN=784, NOUT=40
// out layout: [spk_rec (255*256*40) | mem_rec (255*256*40)] fp32
#define T_STEPS 255
#define BATCH 256
#define NIN 784
#define NOUT 40
#define MROWS (T_STEPS * BATCH)          // 65280
#define TBN (T_STEPS * BATCH * NOUT)     // 2611200
#define BN_CH (BATCH * NOUT)             // 10240

#define BM 128        // rows per block -> grid 510 (validated 107us cfg)
#define NCH 25        // K padded to 800 = 25 chunks of 32
#define WB_CHUNK 4608 // bf16 per chunk: 3 splits x 3 ntiles x 64 lanes x 8
#define EPS_NEAR 2e-4f
#define SCH 30        // scan chunk length (measured-best cfg)

typedef short bf16x8 __attribute__((ext_vector_type(8)));
typedef float f32x4 __attribute__((ext_vector_type(4)));

__device__ __forceinline__ unsigned short f2bf(float f) {  // RNE (W-side)
  unsigned u = __float_as_uint(f);
  u += 0x7fffu + ((u >> 16) & 1u);
  return (unsigned short)(u >> 16);
}
__device__ __forceinline__ float bf2f(unsigned short h) {
  return __uint_as_float(((unsigned)h) << 16);
}

// Pre-split W into fragment-major bf16 (3 exact-residual levels, RNE —
// one-time cost). 230 KB.
__global__ __launch_bounds__(256) void wsplit_kernel(
    const float* __restrict__ W, unsigned short* __restrict__ Wbg,
    int* __restrict__ count) {
  int i = blockIdx.x * 256 + threadIdx.x;
  if (i == 0) *count = 0;
  if (i >= NCH * WB_CHUNK) return;
  int e = i & 7, l = (i >> 3) & 63, t = (i >> 9) % 3, s = (i / 1536) % 3,
      c = i / 4608;
  int k = c * 32 + (l >> 4) * 8 + e;
  int n = t * 16 + (l & 15);
  float v = (n < NOUT && k < NIN) ? W[n * NIN + k] : 0.f;
  unsigned short h1 = f2bf(v);
  float r1 = v - bf2f(h1);
  unsigned short h2 = f2bf(r1);
  float r2 = r1 - bf2f(h2);
  unsigned short h3 = f2bf(r2);
  Wbg[i] = (s == 0) ? h1 : (s == 1) ? h2 : h3;
}

// Split-precision bf16 MFMA GEMM — structure identical to the R22-measured
// 107.2us kernel. ONE change: the A-side 3-level split now uses TRUNCATION
// (bit-mask) + v_perm packing instead of RNE f2bf: 11 VALU ops/pair vs ~31.
// Residuals stay EXACT (e - trunc(e) is exact); worst cur err ~2e-5, still
// >>-covered by EPS_NEAR=2e-4 + fp64 chainfix.
__global__ __launch_bounds__(256) void lif_gemm_mfma(
    const float* __restrict__ X, const unsigned short* __restrict__ Wbg,
    float* __restrict__ cur) {
  alignas(16) __shared__ float xs0[4096];  // buf for even chunks
  alignas(16) __shared__ float xs1[4096];  // buf for odd chunks
  const int tid = threadIdx.x;
  const int m0 = blockIdx.x * BM;
  const int w = tid >> 6, l = tid & 63;
  const int lr = l & 15, lg = l >> 4;

  f32x4 acc[2][3];
#pragma unroll
  for (int st = 0; st < 2; ++st)
#pragma unroll
    for (int t = 0; t < 3; ++t) acc[st][t] = (f32x4){0.f, 0.f, 0.f, 0.f};

  float4 gxA[4], gxB[4];
  bf16x8 BA[9], BB[9];

// LDS-ordered barrier without the vmcnt(0) drain (R22: neutral-validated).
#define BAR()                                                             \
  do {                                                                    \
    asm volatile("s_waitcnt lgkmcnt(0)" ::: "memory");                    \
    __builtin_amdgcn_s_barrier();                                         \
  } while (0)

#define LOADX(C, DST)                                                     \
  do {                                                                    \
    const int k0_ = (C) * 32;                                             \
    _Pragma("unroll")                                                     \
    for (int i = 0; i < 4; ++i) {                                         \
      int S = tid + i * 256;                                              \
      int row = S >> 3;                                                   \
      int c4 = (S & 7) ^ (row & 7);                                       \
      int k = k0_ + c4 * 4;                                               \
      float4 v = make_float4(0.f, 0.f, 0.f, 0.f);                         \
      if (k < NIN)                                                        \
        v = *reinterpret_cast<const float4*>(X + (size_t)(m0 + row) * NIN + k); \
      DST[i] = v;                                                         \
    }                                                                     \
  } while (0)

#define LOADB(C, DST)                                                     \
  do {                                                                    \
    const unsigned short* base_ = Wbg + (size_t)(C) * WB_CHUNK;           \
    _Pragma("unroll")                                                     \
    for (int q = 0; q < 9; ++q)                                           \
      DST[q] = *reinterpret_cast<const bf16x8*>(base_ + (q * 64 + l) * 8); \
  } while (0)

#define WRITEX(BUF, SRC)                                                  \
  do {                                                                    \
    _Pragma("unroll")                                                     \
    for (int i = 0; i < 4; ++i) {                                         \
      int S = tid + i * 256;                                              \
      *reinterpret_cast<float4*>(&(BUF)[S * 4]) = SRC[i];                 \
    }                                                                     \
  } while (0)

// Truncation split of float pair (e0,e1) -> 3 packed bf16x2 dwords.
// h = bits&0xFFFF0000 is the bf16 truncation; e-h is EXACT (Sterbenz);
// pack = v_perm_b32 of the two high-halves.
#define COMPUTE(BUF, BSET)                                                \
  do {                                                                    \
    _Pragma("unroll")                                                     \
    for (int st = 0; st < 2; ++st) {                                      \
      int row = (w + st * 4) * 16 + lr;                                   \
      int sA = row * 8 + ((lg * 2) ^ (row & 7));                          \
      int sB = row * 8 + ((lg * 2 + 1) ^ (row & 7));                      \
      float4 fa = *reinterpret_cast<float4*>(&(BUF)[sA * 4]);             \
      float4 fb = *reinterpret_cast<float4*>(&(BUF)[sB * 4]);             \
      float f[8] = {fa.x, fa.y, fa.z, fa.w, fb.x, fb.y, fb.z, fb.w};      \
      union U { unsigned d[4]; bf16x8 v; } A1, A2, A3;                    \
      _Pragma("unroll")                                                   \
      for (int d = 0; d < 4; ++d) {                                       \
        float e0 = f[2 * d], e1 = f[2 * d + 1];                           \
        unsigned u0 = __float_as_uint(e0), u1 = __float_as_uint(e1);      \
        A1.d[d] = __builtin_amdgcn_perm(u1, u0, 0x07060302u);             \
        float r0 = e0 - __uint_as_float(u0 & 0xFFFF0000u);                \
        float r1 = e1 - __uint_as_float(u1 & 0xFFFF0000u);                \
        unsigned v0 = __float_as_uint(r0), v1 = __float_as_uint(r1);      \
        A2.d[d] = __builtin_amdgcn_perm(v1, v0, 0x07060302u);             \
        float s0 = r0 - __uint_as_float(v0 & 0xFFFF0000u);                \
        float s1 = r1 - __uint_as_float(v1 & 0xFFFF0000u);                \
        A3.d[d] = __builtin_amdgcn_perm(__float_as_uint(s1),              \
                                        __float_as_uint(s0), 0x07060302u);\
      }                                                                   \
      _Pragma("unroll")                                                   \
      for (int t = 0; t < 3; ++t) {                                       \
        acc[st][t] = __builtin_amdgcn_mfma_f32_16x16x32_bf16(A3.v, BSET[0 * 3 + t], acc[st][t], 0, 0, 0); \
        acc[st][t] = __builtin_amdgcn_mfma_f32_16x16x32_bf16(A1.v, BSET[2 * 3 + t], acc[st][t], 0, 0, 0); \
        acc[st][t] = __builtin_amdgcn_mfma_f32_16x16x32_bf16(A2.v, BSET[1 * 3 + t], acc[st][t], 0, 0, 0); \
        acc[st][t] = __builtin_amdgcn_mfma_f32_16x16x32_bf16(A2.v, BSET[0 * 3 + t], acc[st][t], 0, 0, 0); \
        acc[st][t] = __builtin_amdgcn_mfma_f32_16x16x32_bf16(A1.v, BSET[1 * 3 + t], acc[st][t], 0, 0, 0); \
        acc[st][t] = __builtin_amdgcn_mfma_f32_16x16x32_bf16(A1.v, BSET[0 * 3 + t], acc[st][t], 0, 0, 0); \
      }                                                                   \
    }                                                                     \
  } while (0)

  // prologue: chunk0 -> buf0, chunk1 -> regs
  LOADX(0, gxA);
  WRITEX(xs0, gxA);
  LOADX(1, gxB);
  LOADB(0, BA);
  LOADB(1, BB);
  BAR();

  // chunks 0..23 in pairs; chunk 24 in epilogue
  for (int c = 0; c < 24; c += 2) {
    if (c + 2 < NCH) LOADX(c + 2, gxA);
    COMPUTE(xs0, BA);
    if (c + 2 < NCH) LOADB(c + 2, BA);
    WRITEX(xs1, gxB);
    BAR();
    if (c + 3 < NCH) LOADX(c + 3, gxB);
    COMPUTE(xs1, BB);
    if (c + 3 < NCH) LOADB(c + 3, BB);
    if (c + 2 < NCH) WRITEX(xs0, gxA);
    BAR();
  }
  COMPUTE(xs0, BA);  // chunk 24
#undef LOADX
#undef LOADB
#undef WRITEX
#undef COMPUTE
#undef BAR

  // D layout (m89-verified): col = lane&15, row = (lane>>4)*4 + reg
#pragma unroll
  for (int st = 0; st < 2; ++st)
#pragma unroll
    for (int t = 0; t < 3; ++t)
#pragma unroll
      for (int r = 0; r < 4; ++r) {
        int col = t * 16 + lr;
        if (col < NOUT) {
          size_t grow = (size_t)m0 + (w + st * 4) * 16 + lg * 4 + r;
          cur[grow * NOUT + col] = acc[st][t][r];
        }
      }
}

// Validated scan math + near-boundary chain flagging; 30-step chunks with
// next-chunk prefetch (measured-best config).
__global__ __launch_bounds__(64) void lif_scan_kernel(
    float* __restrict__ spk, float* __restrict__ curmem,
    int* __restrict__ count, int* __restrict__ wlist) {
  const int idx = blockIdx.x * 64 + threadIdx.x;
  float mem = 0.f;
  bool near = false;
  float c[SCH];
#pragma unroll
  for (int i = 0; i < SCH; ++i) c[i] = curmem[(size_t)i * BN_CH + idx];
  for (int ch = 0; ch < 9; ++ch) {
    const int t0 = ch * SCH;
    float nx[SCH];
    if (ch != 8) {
#pragma unroll
      for (int i = 0; i < SCH; ++i) {
        int t = t0 + SCH + i;
        nx[i] = (t < T_STEPS) ? curmem[(size_t)t * BN_CH + idx] : 0.f;
      }
    }
#pragma unroll
    for (int i = 0; i < SCH; ++i) {
      if (t0 + i < T_STEPS) {
        float reset = (mem > 1.0f) ? 1.0f : 0.0f;
        float decay = 0.95f * mem;
        asm volatile("" : "+v"(decay));  // forbid fma contraction
        float summ = decay + c[i];
        float mnew = summ * (1.0f - reset);
        near = near || (fabsf(mnew - 1.0f) < EPS_NEAR);
        curmem[(size_t)(t0 + i) * BN_CH + idx] = mnew;
        spk[(size_t)(t0 + i) * BN_CH + idx] = (mnew > 1.0f) ? 1.0f : 0.0f;
        mem = mnew;
      }
    }
    if (ch != 8) {
#pragma unroll
      for (int i = 0; i < SCH; ++i) c[i] = nx[i];
    }
  }
  if (near) {
    int p = atomicAdd(count, 1);
    wlist[p] = idx;
  }
}

// PARALLEL chain re-dot (validated path): one wave per (flagged chain,
// 8-t block), grid-strided; fp64 dot rounded to fp32 into curfix.
__global__ __launch_bounds__(256) void chaindot_kernel(
    const float* __restrict__ X, const float* __restrict__ W,
    const int* __restrict__ count, const int* __restrict__ wlist,
    float* __restrict__ curfix) {
  const int wv0 = blockIdx.x * 4 + (threadIdx.x >> 6);
  const int l = threadIdx.x & 63;
  const int njobs = *count * 32;
  for (int job = wv0; job < njobs; job += 10240) {
    const int f = job >> 5;
    const int tb = (job & 31) * 8;
    const int idx = wlist[f];
    const int b = idx / NOUT, n = idx % NOUT;
    double wreg[13];
#pragma unroll
    for (int j = 0; j < 12; ++j) wreg[j] = (double)W[n * NIN + l + j * 64];
    wreg[12] = (l < 16) ? (double)W[n * NIN + 768 + l] : 0.0;
#pragma unroll
    for (int u = 0; u < 8; ++u) {
      int t = tb + u;
      if (t >= T_STEPS) break;
      const float* xr = X + (size_t)(t * BATCH + b) * NIN;
      double s = 0.0;
#pragma unroll
      for (int j = 0; j < 12; ++j) s = fma((double)xr[l + j * 64], wreg[j], s);
      if (l < 16) s = fma((double)xr[768 + l], wreg[12], s);
#pragma unroll
      for (int off = 32; off; off >>= 1) s += __shfl_xor(s, off);
      if (l == 0) curfix[(size_t)f * T_STEPS + t] = (float)s;
    }
  }
}

// Serial scan replay for flagged chains from curfix (15-deep prefetch);
// overwrites spk/mem (validated path).
__global__ __launch_bounds__(64) void chainscan_kernel(
    float* __restrict__ spk, float* __restrict__ memout,
    const int* __restrict__ count, const int* __restrict__ wlist,
    const float* __restrict__ curfix) {
  const int f = blockIdx.x * 64 + threadIdx.x;
  if (f >= *count) return;
  const int idx = wlist[f];
  const float* cf = curfix + (size_t)f * T_STEPS;
  float mem = 0.f;
  float c[15];
#pragma unroll
  for (int i = 0; i < 15; ++i) c[i] = cf[i];
  for (int ch = 0; ch < 17; ++ch) {
    const int t0 = ch * 15;
    float nx[15];
    if (ch != 16) {
#pragma unroll
      for (int i = 0; i < 15; ++i) nx[i] = cf[t0 + 15 + i];
    }
#pragma unroll
    for (int i = 0; i < 15; ++i) {
      float reset = (mem > 1.0f) ? 1.0f : 0.0f;
      float decay = 0.95f * mem;
      asm volatile("" : "+v"(decay));
      float summ = decay + c[i];
      float mnew = summ * (1.0f - reset);
      spk[(size_t)(t0 + i) * BN_CH + idx] = (mnew > 1.0f) ? 1.0f : 0.0f;
      memout[(size_t)(t0 + i) * BN_CH + idx] = mnew;
      mem = mnew;
    }
    if (ch != 16) {
#pragma unroll
      for (int i = 0; i < 15; ++i) c[i] = nx[i];
    }
  }
}

extern "C" void kernel_launch(void* const* d_in, const int* in_sizes, int n_in,
                              void* d_out, int out_size, void* d_ws,
                              size_t ws_size, hipStream_t stream) {
  (void)in_sizes; (void)n_in; (void)out_size; (void)ws_size;
  const float* X = (const float*)d_in[0];
  const float* W = (const float*)d_in[1];
  float* out = (float*)d_out;
  float* spk = out;            // [255,256,40]
  float* memout = out + TBN;   // [255,256,40]: cur scratch then mem
  char* ws = (char*)d_ws;
  int* count = (int*)ws;
  int* wlist = (int*)(ws + 64);                        // 10240 ints
  unsigned short* Wbg = (unsigned short*)(ws + 41024); // 230400 B
  float* curfix = (float*)(ws + 271424);               // 10240x255 fp32

  wsplit_kernel<<<(NCH * WB_CHUNK + 255) / 256, 256, 0, stream>>>(W, Wbg,
                                                                  count);
  lif_gemm_mfma<<<MROWS / BM, 256, 0, stream>>>(X, Wbg, memout);
  lif_scan_kernel<<<BN_CH / 64, 64, 0, stream>>>(spk, memout, count, wlist);
  chaindot_kernel<<<2560, 256, 0, stream>>>(X, W, count, wlist, curfix);
  chainscan_kernel<<<BN_CH / 64, 64, 0, stream>>>(spk, memout, count, wlist,
                                                  curfix);
}

// Round 25
// 99.803 us; speedup vs baseline: 1.0814x; 1.0031x over previous
//
#include <hip/hip_runtime.h>
#include <hip/hip_bf16.h>

// Problem: T=255, B=256, NIN=784, NOUT=40
// out layout: [spk_rec (255*256*40) | mem_rec (255*256*40)] fp32
#define T_STEPS 255
#define BATCH 256
#define NIN 784
#define NOUT 40
#define MROWS (T_STEPS * BATCH)          // 65280
#define TBN (T_STEPS * BATCH * NOUT)     // 2611200
#define BN_CH (BATCH * NOUT)             // 10240

#define BM 128        // rows per block -> grid 510
#define NCH 25        // K padded to 800 = 25 chunks of 32
#define WB_CHUNK 4608 // bf16 per chunk: 3 splits x 3 ntiles x 64 lanes x 8
#define EPS_NEAR 2e-4f
#define SCH 30        // scan chunk length (measured-best cfg)

typedef short bf16x8 __attribute__((ext_vector_type(8)));
typedef float f32x4 __attribute__((ext_vector_type(4)));

__device__ __forceinline__ unsigned short f2bf(float f) {  // RNE (W-side)
  unsigned u = __float_as_uint(f);
  u += 0x7fffu + ((u >> 16) & 1u);
  return (unsigned short)(u >> 16);
}
__device__ __forceinline__ float bf2f(unsigned short h) {
  return __uint_as_float(((unsigned)h) << 16);
}

// Pre-split W into fragment-major bf16 (3 exact-residual levels, RNE —
// one-time cost). 230 KB.
__global__ __launch_bounds__(256) void wsplit_kernel(
    const float* __restrict__ W, unsigned short* __restrict__ Wbg,
    int* __restrict__ count) {
  int i = blockIdx.x * 256 + threadIdx.x;
  if (i == 0) *count = 0;
  if (i >= NCH * WB_CHUNK) return;
  int e = i & 7, l = (i >> 3) & 63, t = (i >> 9) % 3, s = (i / 1536) % 3,
      c = i / 4608;
  int k = c * 32 + (l >> 4) * 8 + e;
  int n = t * 16 + (l & 15);
  float v = (n < NOUT && k < NIN) ? W[n * NIN + k] : 0.f;
  unsigned short h1 = f2bf(v);
  float r1 = v - bf2f(h1);
  unsigned short h2 = f2bf(r1);
  float r2 = r1 - bf2f(h2);
  unsigned short h3 = f2bf(r2);
  Wbg[i] = (s == 0) ? h1 : (s == 1) ? h2 : h3;
}

// Split-precision bf16 MFMA GEMM — split math / MFMA order byte-identical
// to the R24-validated 100.1us kernel. STRUCTURAL CHANGE: LDS staging
// deleted. The A-fragments partition the X tile 1:1 (zero cross-thread
// reuse), and each fragment is contiguous in X (X[row][k0+lg*8..+7] = two
// adjacent float4s), so threads load fragments DIRECTLY global->reg.
// No __shared__, no barriers, 1-chunk register prefetch.
__global__ __launch_bounds__(256) void lif_gemm_mfma(
    const float* __restrict__ X, const unsigned short* __restrict__ Wbg,
    float* __restrict__ cur) {
  const int tid = threadIdx.x;
  const int m0 = blockIdx.x * BM;
  const int w = tid >> 6, l = tid & 63;
  const int lr = l & 15, lg = l >> 4;

  // per-thread fragment row pointers (st=0: rows 0..63; st=1: rows 64..127)
  const float* xp0 = X + (size_t)(m0 + w * 16 + lr) * NIN;
  const float* xp1 = xp0 + (size_t)64 * NIN;

  f32x4 acc[2][3];
#pragma unroll
  for (int st = 0; st < 2; ++st)
#pragma unroll
    for (int t = 0; t < 3; ++t) acc[st][t] = (f32x4){0.f, 0.f, 0.f, 0.f};

  float4 gxA[4], gxB[4];  // [st*2+half]: fa/fb fragments for 2 row-subtiles
  bf16x8 BA[9], BB[9];

#define LOADXD(C, DST)                                                    \
  do {                                                                    \
    const int kb = (C) * 32 + lg * 8;                                     \
    DST[0] = (kb < NIN)                                                   \
        ? *reinterpret_cast<const float4*>(xp0 + kb)                      \
        : make_float4(0.f, 0.f, 0.f, 0.f);                                \
    DST[1] = (kb + 4 < NIN)                                               \
        ? *reinterpret_cast<const float4*>(xp0 + kb + 4)                  \
        : make_float4(0.f, 0.f, 0.f, 0.f);                                \
    DST[2] = (kb < NIN)                                                   \
        ? *reinterpret_cast<const float4*>(xp1 + kb)                      \
        : make_float4(0.f, 0.f, 0.f, 0.f);                                \
    DST[3] = (kb + 4 < NIN)                                               \
        ? *reinterpret_cast<const float4*>(xp1 + kb + 4)                  \
        : make_float4(0.f, 0.f, 0.f, 0.f);                                \
  } while (0)

#define LOADB(C, DST)                                                     \
  do {                                                                    \
    const unsigned short* base_ = Wbg + (size_t)(C) * WB_CHUNK;           \
    _Pragma("unroll")                                                     \
    for (int q = 0; q < 9; ++q)                                           \
      DST[q] = *reinterpret_cast<const bf16x8*>(base_ + (q * 64 + l) * 8); \
  } while (0)

// Truncation split (R24-validated) of the fragment pair -> 3 bf16x8 levels,
// then the 6-term MFMA ladder in the validated order.
#define COMPUTE(GX, BSET)                                                 \
  do {                                                                    \
    _Pragma("unroll")                                                     \
    for (int st = 0; st < 2; ++st) {                                      \
      float4 fa = GX[st * 2];                                             \
      float4 fb = GX[st * 2 + 1];                                         \
      float f[8] = {fa.x, fa.y, fa.z, fa.w, fb.x, fb.y, fb.z, fb.w};      \
      union U { unsigned d[4]; bf16x8 v; } A1, A2, A3;                    \
      _Pragma("unroll")                                                   \
      for (int d = 0; d < 4; ++d) {                                       \
        float e0 = f[2 * d], e1 = f[2 * d + 1];                           \
        unsigned u0 = __float_as_uint(e0), u1 = __float_as_uint(e1);      \
        A1.d[d] = __builtin_amdgcn_perm(u1, u0, 0x07060302u);             \
        float r0 = e0 - __uint_as_float(u0 & 0xFFFF0000u);                \
        float r1 = e1 - __uint_as_float(u1 & 0xFFFF0000u);                \
        unsigned v0 = __float_as_uint(r0), v1 = __float_as_uint(r1);      \
        A2.d[d] = __builtin_amdgcn_perm(v1, v0, 0x07060302u);             \
        float s0 = r0 - __uint_as_float(v0 & 0xFFFF0000u);                \
        float s1 = r1 - __uint_as_float(v1 & 0xFFFF0000u);                \
        A3.d[d] = __builtin_amdgcn_perm(__float_as_uint(s1),              \
                                        __float_as_uint(s0), 0x07060302u);\
      }                                                                   \
      _Pragma("unroll")                                                   \
      for (int t = 0; t < 3; ++t) {                                       \
        acc[st][t] = __builtin_amdgcn_mfma_f32_16x16x32_bf16(A3.v, BSET[0 * 3 + t], acc[st][t], 0, 0, 0); \
        acc[st][t] = __builtin_amdgcn_mfma_f32_16x16x32_bf16(A1.v, BSET[2 * 3 + t], acc[st][t], 0, 0, 0); \
        acc[st][t] = __builtin_amdgcn_mfma_f32_16x16x32_bf16(A2.v, BSET[1 * 3 + t], acc[st][t], 0, 0, 0); \
        acc[st][t] = __builtin_amdgcn_mfma_f32_16x16x32_bf16(A2.v, BSET[0 * 3 + t], acc[st][t], 0, 0, 0); \
        acc[st][t] = __builtin_amdgcn_mfma_f32_16x16x32_bf16(A1.v, BSET[1 * 3 + t], acc[st][t], 0, 0, 0); \
        acc[st][t] = __builtin_amdgcn_mfma_f32_16x16x32_bf16(A1.v, BSET[0 * 3 + t], acc[st][t], 0, 0, 0); \
      }                                                                   \
    }                                                                     \
  } while (0)

  // prologue: chunks 0,1 -> regs (no barriers anywhere)
  LOADXD(0, gxA);
  LOADB(0, BA);
  LOADXD(1, gxB);
  LOADB(1, BB);

  // compute c, then reload its regs with c+2 (1-chunk prefetch distance;
  // compiler inserts counted vmcnt waits at first use)
  for (int c = 0; c < 24; c += 2) {
    COMPUTE(gxA, BA);
    if (c + 2 < NCH) { LOADXD(c + 2, gxA); LOADB(c + 2, BA); }
    COMPUTE(gxB, BB);
    if (c + 3 < NCH) { LOADXD(c + 3, gxB); LOADB(c + 3, BB); }
  }
  COMPUTE(gxA, BA);  // chunk 24
#undef LOADXD
#undef LOADB
#undef COMPUTE

  // D layout (m89-verified): col = lane&15, row = (lane>>4)*4 + reg
#pragma unroll
  for (int st = 0; st < 2; ++st)
#pragma unroll
    for (int t = 0; t < 3; ++t)
#pragma unroll
      for (int r = 0; r < 4; ++r) {
        int col = t * 16 + lr;
        if (col < NOUT) {
          size_t grow = (size_t)m0 + (w + st * 4) * 16 + lg * 4 + r;
          cur[grow * NOUT + col] = acc[st][t][r];
        }
      }
}

// Validated scan math + near-boundary chain flagging; 30-step chunks with
// next-chunk prefetch (measured-best config).
__global__ __launch_bounds__(64) void lif_scan_kernel(
    float* __restrict__ spk, float* __restrict__ curmem,
    int* __restrict__ count, int* __restrict__ wlist) {
  const int idx = blockIdx.x * 64 + threadIdx.x;
  float mem = 0.f;
  bool near = false;
  float c[SCH];
#pragma unroll
  for (int i = 0; i < SCH; ++i) c[i] = curmem[(size_t)i * BN_CH + idx];
  for (int ch = 0; ch < 9; ++ch) {
    const int t0 = ch * SCH;
    float nx[SCH];
    if (ch != 8) {
#pragma unroll
      for (int i = 0; i < SCH; ++i) {
        int t = t0 + SCH + i;
        nx[i] = (t < T_STEPS) ? curmem[(size_t)t * BN_CH + idx] : 0.f;
      }
    }
#pragma unroll
    for (int i = 0; i < SCH; ++i) {
      if (t0 + i < T_STEPS) {
        float reset = (mem > 1.0f) ? 1.0f : 0.0f;
        float decay = 0.95f * mem;
        asm volatile("" : "+v"(decay));  // forbid fma contraction
        float summ = decay + c[i];
        float mnew = summ * (1.0f - reset);
        near = near || (fabsf(mnew - 1.0f) < EPS_NEAR);
        curmem[(size_t)(t0 + i) * BN_CH + idx] = mnew;
        spk[(size_t)(t0 + i) * BN_CH + idx] = (mnew > 1.0f) ? 1.0f : 0.0f;
        mem = mnew;
      }
    }
    if (ch != 8) {
#pragma unroll
      for (int i = 0; i < SCH; ++i) c[i] = nx[i];
    }
  }
  if (near) {
    int p = atomicAdd(count, 1);
    wlist[p] = idx;
  }
}

// PARALLEL chain re-dot (validated path): one wave per (flagged chain,
// 8-t block), grid-strided; fp64 dot rounded to fp32 into curfix.
__global__ __launch_bounds__(256) void chaindot_kernel(
    const float* __restrict__ X, const float* __restrict__ W,
    const int* __restrict__ count, const int* __restrict__ wlist,
    float* __restrict__ curfix) {
  const int wv0 = blockIdx.x * 4 + (threadIdx.x >> 6);
  const int l = threadIdx.x & 63;
  const int njobs = *count * 32;
  for (int job = wv0; job < njobs; job += 10240) {
    const int f = job >> 5;
    const int tb = (job & 31) * 8;
    const int idx = wlist[f];
    const int b = idx / NOUT, n = idx % NOUT;
    double wreg[13];
#pragma unroll
    for (int j = 0; j < 12; ++j) wreg[j] = (double)W[n * NIN + l + j * 64];
    wreg[12] = (l < 16) ? (double)W[n * NIN + 768 + l] : 0.0;
#pragma unroll
    for (int u = 0; u < 8; ++u) {
      int t = tb + u;
      if (t >= T_STEPS) break;
      const float* xr = X + (size_t)(t * BATCH + b) * NIN;
      double s = 0.0;
#pragma unroll
      for (int j = 0; j < 12; ++j) s = fma((double)xr[l + j * 64], wreg[j], s);
      if (l < 16) s = fma((double)xr[768 + l], wreg[12], s);
#pragma unroll
      for (int off = 32; off; off >>= 1) s += __shfl_xor(s, off);
      if (l == 0) curfix[(size_t)f * T_STEPS + t] = (float)s;
    }
  }
}

// Serial scan replay for flagged chains from curfix (15-deep prefetch);
// overwrites spk/mem (validated path).
__global__ __launch_bounds__(64) void chainscan_kernel(
    float* __restrict__ spk, float* __restrict__ memout,
    const int* __restrict__ count, const int* __restrict__ wlist,
    const float* __restrict__ curfix) {
  const int f = blockIdx.x * 64 + threadIdx.x;
  if (f >= *count) return;
  const int idx = wlist[f];
  const float* cf = curfix + (size_t)f * T_STEPS;
  float mem = 0.f;
  float c[15];
#pragma unroll
  for (int i = 0; i < 15; ++i) c[i] = cf[i];
  for (int ch = 0; ch < 17; ++ch) {
    const int t0 = ch * 15;
    float nx[15];
    if (ch != 16) {
#pragma unroll
      for (int i = 0; i < 15; ++i) nx[i] = cf[t0 + 15 + i];
    }
#pragma unroll
    for (int i = 0; i < 15; ++i) {
      float reset = (mem > 1.0f) ? 1.0f : 0.0f;
      float decay = 0.95f * mem;
      asm volatile("" : "+v"(decay));
      float summ = decay + c[i];
      float mnew = summ * (1.0f - reset);
      spk[(size_t)(t0 + i) * BN_CH + idx] = (mnew > 1.0f) ? 1.0f : 0.0f;
      memout[(size_t)(t0 + i) * BN_CH + idx] = mnew;
      mem = mnew;
    }
    if (ch != 16) {
#pragma unroll
      for (int i = 0; i < 15; ++i) c[i] = nx[i];
    }
  }
}

extern "C" void kernel_launch(void* const* d_in, const int* in_sizes, int n_in,
                              void* d_out, int out_size, void* d_ws,
                              size_t ws_size, hipStream_t stream) {
  (void)in_sizes; (void)n_in; (void)out_size; (void)ws_size;
  const float* X = (const float*)d_in[0];
  const float* W = (const float*)d_in[1];
  float* out = (float*)d_out;
  float* spk = out;            // [255,256,40]
  float* memout = out + TBN;   // [255,256,40]: cur scratch then mem
  char* ws = (char*)d_ws;
  int* count = (int*)ws;
  int* wlist = (int*)(ws + 64);                        // 10240 ints
  unsigned short* Wbg = (unsigned short*)(ws + 41024); // 230400 B
  float* curfix = (float*)(ws + 271424);               // 10240x255 fp32

  wsplit_kernel<<<(NCH * WB_CHUNK + 255) / 256, 256, 0, stream>>>(W, Wbg,
                                                                  count);
  lif_gemm_mfma<<<MROWS / BM, 256, 0, stream>>>(X, Wbg, memout);
  lif_scan_kernel<<<BN_CH / 64, 64, 0, stream>>>(spk, memout, count, wlist);
  chaindot_kernel<<<2560, 256, 0, stream>>>(X, W, count, wlist, curfix);
  chainscan_kernel<<<BN_CH / 64, 64, 0, stream>>>(spk, memout, count, wlist,
                                                  curfix);
}